// Round 1
// baseline (4009.992 us; speedup 1.0000x reference)
//
#include <hip/hip_runtime.h>

// QFF: 2M points, 16 freqs x {sin,cos} = 32 groups, trilinear gather from
// cv[g][c][64][64][64], output (N, 3 + 64) float32.
//
// Round 1 strategy:
//  - repack cv -> cvp[g][z][y][x] = float2{c0,c1} in d_ws (channel interleave):
//    halves gather count and cache-line traffic, all gathers 8B-aligned dwordx2.
//  - one thread per point; factorized trilinear lerp; native sin/cos.

constexpr int NF = 16;
constexpr int G  = 32;
constexpr int Q  = 64;
constexpr int QV = Q * Q * Q;     // 262144 voxels per (g,c) volume
constexpr int OUTW = 3 + G * 2;   // 67 floats per point

__global__ __launch_bounds__(256) void reorder_cv_kernel(
    const float* __restrict__ cv, float2* __restrict__ cvp, int total) {
  int i = blockIdx.x * blockDim.x + threadIdx.x;
  if (i >= total) return;
  int g = i >> 18;               // i / QV
  int r = i & (QV - 1);
  size_t b = ((size_t)(g * 2)) << 18;   // base of cv[g][0]
  cvp[i] = make_float2(cv[b + r], cv[b + QV + r]);
}

__device__ __forceinline__ float2 lerp2(float2 a, float2 b, float w) {
  return make_float2(a.x + w * (b.x - a.x), a.y + w * (b.y - a.y));
}

template <bool PACKED>
__global__ __launch_bounds__(256) void qff_kernel(
    const float* __restrict__ pts,
    const float* __restrict__ freqs,
    const float* __restrict__ cv,      // original layout (fallback)
    const float2* __restrict__ cvp,    // packed layout
    float* __restrict__ out, int N) {
  int n = blockIdx.x * blockDim.x + threadIdx.x;
  if (n >= N) return;

  float p0 = pts[3 * n + 0];
  float p1 = pts[3 * n + 1];
  float p2 = pts[3 * n + 2];

  float* o = out + (size_t)n * OUTW;
  o[0] = p0; o[1] = p1; o[2] = p2;

#pragma unroll 1
  for (int f = 0; f < NF; ++f) {
    float fr = freqs[f];                 // uniform -> scalar load
    float ph0 = p0 * fr, ph1 = p1 * fr, ph2 = p2 * fr;
    float s0 = __sinf(ph0), c0 = __cosf(ph0);
    float s1 = __sinf(ph1), c1 = __cosf(ph1);
    float s2 = __sinf(ph2), c2 = __cosf(ph2);

#pragma unroll
    for (int s = 0; s < 2; ++s) {
      int g = 2 * f + s;
      // dim0 -> z (slowest), dim1 -> y, dim2 -> x (fastest), matching
      // cv[g, c, iz, iy, ix] in the reference.
      float cz = s ? c0 : s0;
      float cy = s ? c1 : s1;
      float cx = s ? c2 : s2;

      float xz = (cz + 1.0f) * 31.5f;
      float xy = (cy + 1.0f) * 31.5f;
      float xx = (cx + 1.0f) * 31.5f;

      float fz = floorf(xz), fy = floorf(xy), fx = floorf(xx);
      float wz = xz - fz, wy = xy - fy, wx = xx - fx;

      int iz = min(max((int)fz, 0), Q - 2);
      int iy = min(max((int)fy, 0), Q - 2);
      int ix = min(max((int)fx, 0), Q - 2);

      int off = (iz * Q + iy) * Q + ix;

      float2 a00, a01, a10, a11, b00, b01, b10, b11;
      if (PACKED) {
        const float2* base = cvp + ((size_t)g << 18);
        a00 = base[off];             a01 = base[off + 1];
        a10 = base[off + Q];         a11 = base[off + Q + 1];
        b00 = base[off + Q * Q];     b01 = base[off + Q * Q + 1];
        b10 = base[off + Q * Q + Q]; b11 = base[off + Q * Q + Q + 1];
      } else {
        const float* v0 = cv + (((size_t)(g * 2)) << 18);
        const float* v1 = v0 + QV;
        a00 = make_float2(v0[off], v1[off]);
        a01 = make_float2(v0[off + 1], v1[off + 1]);
        a10 = make_float2(v0[off + Q], v1[off + Q]);
        a11 = make_float2(v0[off + Q + 1], v1[off + Q + 1]);
        b00 = make_float2(v0[off + Q * Q], v1[off + Q * Q]);
        b01 = make_float2(v0[off + Q * Q + 1], v1[off + Q * Q + 1]);
        b10 = make_float2(v0[off + Q * Q + Q], v1[off + Q * Q + Q]);
        b11 = make_float2(v0[off + Q * Q + Q + 1], v1[off + Q * Q + Q + 1]);
      }

      // factorized trilinear: x, then y, then z (== corner-weight sum)
      float2 l00 = lerp2(a00, a01, wx);
      float2 l01 = lerp2(a10, a11, wx);
      float2 l10 = lerp2(b00, b01, wx);
      float2 l11 = lerp2(b10, b11, wx);
      float2 m0 = lerp2(l00, l01, wy);
      float2 m1 = lerp2(l10, l11, wy);
      float2 r  = lerp2(m0, m1, wz);

      o[3 + 2 * g]     = r.x;
      o[3 + 2 * g + 1] = r.y;
    }
  }
}

extern "C" void kernel_launch(void* const* d_in, const int* in_sizes, int n_in,
                              void* d_out, int out_size, void* d_ws, size_t ws_size,
                              hipStream_t stream) {
  const float* pts   = (const float*)d_in[0];
  const float* freqs = (const float*)d_in[1];
  const float* cv    = (const float*)d_in[2];
  float* out = (float*)d_out;

  int N = in_sizes[0] / 3;

  size_t need = (size_t)G * QV * sizeof(float2);  // 64 MiB
  if (ws_size >= need) {
    float2* cvp = (float2*)d_ws;
    int total = G * QV;
    reorder_cv_kernel<<<(total + 255) / 256, 256, 0, stream>>>(cv, cvp, total);
    qff_kernel<true><<<(N + 255) / 256, 256, 0, stream>>>(pts, freqs, cv, cvp, out, N);
  } else {
    qff_kernel<false><<<(N + 255) / 256, 256, 0, stream>>>(pts, freqs, cv, nullptr, out, N);
  }
}